// Round 1
// baseline (3992.136 us; speedup 1.0000x reference)
//
#include <hip/hip_runtime.h>
#include <math.h>

#define N_NODES 100000
#define N_EDGES 3200000
#define F_IN 256
#define M_OUT 512            // 2*F_OUT concat
#define EPS_BN 1e-3f
#define NUM_CHUNKS 391       // ceil(100000/256)

// ---------------- small utility kernels ----------------

__global__ void zero_i32(int* __restrict__ p, int n) {
    int i = blockIdx.x * blockDim.x + threadIdx.x;
    if (i < n) p[i] = 0;
}

__global__ void hist_kernel(const int* __restrict__ row, int* __restrict__ counts, int n) {
    int i = blockIdx.x * blockDim.x + threadIdx.x;
    if (i < n) atomicAdd(&counts[row[i]], 1);
}

// phase 1: per-chunk (256 elems) sums
__global__ void scan_chunk_sums(const int* __restrict__ counts, int* __restrict__ chunkSums, int n) {
    __shared__ int sm[256];
    int c = blockIdx.x;
    int t = threadIdx.x;
    int i = c * 256 + t;
    sm[t] = (i < n) ? counts[i] : 0;
    __syncthreads();
    for (int s = 128; s > 0; s >>= 1) {
        if (t < s) sm[t] += sm[t + s];
        __syncthreads();
    }
    if (t == 0) chunkSums[c] = sm[0];
}

// phase 2: exclusive scan of chunk sums (numChunks <= 512), one block
__global__ void scan_spine(int* __restrict__ chunkSums, int numChunks, int* __restrict__ row_off, int n) {
    __shared__ int sm[512];
    int t = threadIdx.x;
    int v = (t < numChunks) ? chunkSums[t] : 0;
    sm[t] = v;
    __syncthreads();
    for (int s = 1; s < 512; s <<= 1) {
        int add = (t >= s) ? sm[t - s] : 0;
        __syncthreads();
        sm[t] += add;
        __syncthreads();
    }
    if (t < numChunks) chunkSums[t] = sm[t] - v;   // exclusive
    if (t == 511) row_off[n] = sm[511];            // total edges
}

// phase 3: per-chunk exclusive scan + spine offset -> row_off
__global__ void scan_final(const int* __restrict__ counts, const int* __restrict__ chunkSums,
                           int* __restrict__ row_off, int n) {
    __shared__ int sm[256];
    int c = blockIdx.x;
    int t = threadIdx.x;
    int i = c * 256 + t;
    int v = (i < n) ? counts[i] : 0;
    sm[t] = v;
    __syncthreads();
    for (int s = 1; s < 256; s <<= 1) {
        int add = (t >= s) ? sm[t - s] : 0;
        __syncthreads();
        sm[t] += add;
        __syncthreads();
    }
    if (i < n) row_off[i] = chunkSums[c] + sm[t] - v;
}

__global__ void scatter_kernel(const int* __restrict__ row, const int* __restrict__ col,
                               const float* __restrict__ val,
                               const int* __restrict__ row_off, int* __restrict__ cursor,
                               int* __restrict__ col_s, float* __restrict__ val_s, int n) {
    int i = blockIdx.x * blockDim.x + threadIdx.x;
    if (i < n) {
        int r = row[i];
        int pos = row_off[r] + atomicAdd(&cursor[r], 1);
        col_s[pos] = col[i];
        val_s[pos] = val[i];
    }
}

// ---------------- SpMM: one wave per row, float4 per lane ----------------

__global__ void spmm_kernel(const int* __restrict__ row_off, const int* __restrict__ col_s,
                            const float* __restrict__ val_s,
                            const float* __restrict__ h, float* __restrict__ y) {
    int wave = threadIdx.x >> 6;
    int lane = threadIdx.x & 63;
    int row = blockIdx.x * 4 + wave;
    if (row >= N_NODES) return;
    int s = row_off[row];
    int e = row_off[row + 1];
    float4 acc = make_float4(0.f, 0.f, 0.f, 0.f);
    for (int j = s; j < e; j++) {
        int c = col_s[j];
        float v = val_s[j];
        const float4 hv = *reinterpret_cast<const float4*>(&h[(size_t)c * F_IN + lane * 4]);
        acc.x += v * hv.x;
        acc.y += v * hv.y;
        acc.z += v * hv.z;
        acc.w += v * hv.w;
    }
    *reinterpret_cast<float4*>(&y[(size_t)row * F_IN + lane * 4]) = acc;
}

// ---------------- weight / BN prep ----------------

// Wc: [4][256][512] contiguous. seg 0 = sum_j w{a,b}_x[j]; seg s=1..3 = w{a,b}_adj[s-1]
__global__ void build_weights(const float* __restrict__ wa_x, const float* __restrict__ wa_adj,
                              const float* __restrict__ wb_x, const float* __restrict__ wb_adj,
                              float* __restrict__ Wc) {
    int idx = blockIdx.x * blockDim.x + threadIdx.x;
    if (idx >= 1024 * 512) return;
    int kk = idx >> 9;        // 0..1023
    int m = idx & 511;        // 0..511
    int seg = kk >> 8;
    int k = kk & 255;
    float w;
    if (seg == 0) {
        if (m < 256)
            w = wa_x[0 * 65536 + k * 256 + m] + wa_x[1 * 65536 + k * 256 + m] + wa_x[2 * 65536 + k * 256 + m];
        else {
            int mm = m - 256;
            w = wb_x[0 * 65536 + k * 256 + mm] + wb_x[1 * 65536 + k * 256 + mm] + wb_x[2 * 65536 + k * 256 + mm];
        }
    } else {
        int s = seg - 1;
        if (m < 256) w = wa_adj[s * 65536 + k * 256 + m];
        else         w = wb_adj[s * 65536 + k * 256 + (m - 256)];
    }
    Wc[idx] = w;
}

__global__ void build_bn(const float* __restrict__ ga, const float* __restrict__ ba,
                         const float* __restrict__ ma, const float* __restrict__ va,
                         const float* __restrict__ gb, const float* __restrict__ bb,
                         const float* __restrict__ mb, const float* __restrict__ vb,
                         float* __restrict__ scale, float* __restrict__ bias) {
    int c = blockIdx.x * blockDim.x + threadIdx.x;
    if (c >= 512) return;
    float g, b, m, v;
    if (c < 256) { g = ga[c]; b = ba[c]; m = ma[c]; v = va[c]; }
    else { int cc = c - 256; g = gb[cc]; b = bb[cc]; m = mb[cc]; v = vb[cc]; }
    float s = g / sqrtf(v + EPS_BN);
    scale[c] = s;
    bias[c] = b - m * s;
}

// ---------------- fp32 tiled GEMM: C[N,512] (+)= A[N,256] @ B[256,512] ----------------
// ACC: accumulate into C. EPI: apply relu (cols<256) then BN affine on final write.

template <bool ACC, bool EPI>
__global__ void gemm64(const float* __restrict__ A, const float* __restrict__ B,
                       float* __restrict__ C,
                       const float* __restrict__ scale, const float* __restrict__ bias) {
    __shared__ float As[16][65];
    __shared__ float Bs[16][68];
    int tid = threadIdx.x;
    int tx = tid & 15;
    int ty = tid >> 4;
    int mBase = blockIdx.y * 64;
    int nBase = blockIdx.x * 64;
    float acc[4][4] = {};

    for (int k0 = 0; k0 < 256; k0 += 16) {
#pragma unroll
        for (int i = 0; i < 4; i++) {
            int lin = tid + i * 256;
            int m = lin >> 4, k = lin & 15;
            int gm = mBase + m;
            As[k][m] = (gm < N_NODES) ? A[(size_t)gm * 256 + k0 + k] : 0.f;
        }
#pragma unroll
        for (int i = 0; i < 4; i++) {
            int lin = tid + i * 256;
            int k = lin >> 6, n = lin & 63;
            Bs[k][n] = B[(size_t)(k0 + k) * 512 + nBase + n];
        }
        __syncthreads();
#pragma unroll
        for (int k = 0; k < 16; k++) {
            float a[4], b[4];
#pragma unroll
            for (int i = 0; i < 4; i++) a[i] = As[k][ty * 4 + i];
#pragma unroll
            for (int j = 0; j < 4; j++) b[j] = Bs[k][tx * 4 + j];
#pragma unroll
            for (int i = 0; i < 4; i++)
#pragma unroll
                for (int j = 0; j < 4; j++) acc[i][j] += a[i] * b[j];
        }
        __syncthreads();
    }

#pragma unroll
    for (int i = 0; i < 4; i++) {
        int gm = mBase + ty * 4 + i;
        if (gm >= N_NODES) continue;
#pragma unroll
        for (int j = 0; j < 4; j++) {
            int gn = nBase + tx * 4 + j;
            size_t off = (size_t)gm * 512 + gn;
            float v = acc[i][j];
            if (ACC) v += C[off];
            if (EPI) {
                if (gn < 256) v = fmaxf(v, 0.f);
                v = v * scale[gn] + bias[gn];
            }
            C[off] = v;
        }
    }
}

// ---------------- launch ----------------

static inline size_t align_up(size_t x, size_t a) { return (x + a - 1) & ~(a - 1); }

extern "C" void kernel_launch(void* const* d_in, const int* in_sizes, int n_in,
                              void* d_out, int out_size, void* d_ws, size_t ws_size,
                              hipStream_t stream) {
    const float* x      = (const float*)d_in[0];
    const int*   erow   = (const int*)d_in[1];
    const int*   ecol   = (const int*)d_in[2];
    const float* eval   = (const float*)d_in[3];
    const float* wa_x   = (const float*)d_in[4];
    const float* wa_adj = (const float*)d_in[5];
    const float* wb_x   = (const float*)d_in[6];
    const float* wb_adj = (const float*)d_in[7];
    const float* ga = (const float*)d_in[8];
    const float* ba = (const float*)d_in[9];
    const float* ma = (const float*)d_in[10];
    const float* va = (const float*)d_in[11];
    const float* gb = (const float*)d_in[12];
    const float* bb = (const float*)d_in[13];
    const float* mb = (const float*)d_in[14];
    const float* vb = (const float*)d_in[15];
    float* out = (float*)d_out;

    char* ws = (char*)d_ws;
    size_t off = 0;
    int*   row_off   = (int*)(ws + off); off = align_up(off + (size_t)(N_NODES + 1) * 4, 1024);
    int*   cursor    = (int*)(ws + off); off = align_up(off + (size_t)N_NODES * 4, 1024);
    int*   chunkSums = (int*)(ws + off); off = align_up(off + (size_t)NUM_CHUNKS * 4, 1024);
    int*   col_s     = (int*)(ws + off); off = align_up(off + (size_t)N_EDGES * 4, 1024);
    float* val_s     = (float*)(ws + off); off = align_up(off + (size_t)N_EDGES * 4, 1024);
    float* Wc        = (float*)(ws + off); off = align_up(off + (size_t)1024 * 512 * 4, 1024);
    float* scale     = (float*)(ws + off); off = align_up(off + 512 * 4, 1024);
    float* bias      = (float*)(ws + off); off = align_up(off + 512 * 4, 1024);
    float* H0        = (float*)(ws + off); off = align_up(off + (size_t)N_NODES * F_IN * 4, 1024);
    float* H1        = (float*)(ws + off); off = align_up(off + (size_t)N_NODES * F_IN * 4, 1024);
    (void)ws_size; (void)in_sizes; (void)n_in; (void)out_size;

    const int zeroBlocks = (N_NODES + 255) / 256;
    const int edgeBlocks = (N_EDGES + 255) / 256;

    // ---- CSR build ----
    zero_i32<<<zeroBlocks, 256, 0, stream>>>(cursor, N_NODES);
    hist_kernel<<<edgeBlocks, 256, 0, stream>>>(erow, cursor, N_EDGES);
    scan_chunk_sums<<<NUM_CHUNKS, 256, 0, stream>>>(cursor, chunkSums, N_NODES);
    scan_spine<<<1, 512, 0, stream>>>(chunkSums, NUM_CHUNKS, row_off, N_NODES);
    scan_final<<<NUM_CHUNKS, 256, 0, stream>>>(cursor, chunkSums, row_off, N_NODES);
    zero_i32<<<zeroBlocks, 256, 0, stream>>>(cursor, N_NODES);
    scatter_kernel<<<edgeBlocks, 256, 0, stream>>>(erow, ecol, eval, row_off, cursor,
                                                   col_s, val_s, N_EDGES);

    // ---- weight & BN prep ----
    build_weights<<<(1024 * 512) / 256, 256, 0, stream>>>(wa_x, wa_adj, wb_x, wb_adj, Wc);
    build_bn<<<2, 256, 0, stream>>>(ga, ba, ma, va, gb, bb, mb, vb, scale, bias);

    // ---- GEMM 0: C = x @ Wc[seg0] ----
    dim3 gemmGrid(M_OUT / 64, (N_NODES + 63) / 64);
    gemm64<false, false><<<gemmGrid, 256, 0, stream>>>(x, Wc, out, scale, bias);

    const int spmmBlocks = (N_NODES + 3) / 4;
    // hop0 = A x
    spmm_kernel<<<spmmBlocks, 256, 0, stream>>>(row_off, col_s, val_s, x, H0);
    gemm64<true, false><<<gemmGrid, 256, 0, stream>>>(H0, Wc + 1 * 256 * 512, out, scale, bias);
    // hop1 = A^2 x
    spmm_kernel<<<spmmBlocks, 256, 0, stream>>>(row_off, col_s, val_s, H0, H1);
    gemm64<true, false><<<gemmGrid, 256, 0, stream>>>(H1, Wc + 2 * 256 * 512, out, scale, bias);
    // hop2 = A^4 x
    spmm_kernel<<<spmmBlocks, 256, 0, stream>>>(row_off, col_s, val_s, H1, H0); // A^3 x
    spmm_kernel<<<spmmBlocks, 256, 0, stream>>>(row_off, col_s, val_s, H0, H1); // A^4 x
    gemm64<true, true><<<gemmGrid, 256, 0, stream>>>(H1, Wc + 3 * 256 * 512, out, scale, bias);
}

// Round 2
// 2068.050 us; speedup vs baseline: 1.9304x; 1.9304x over previous
//
#include <hip/hip_runtime.h>
#include <math.h>

#define N_NODES 100000
#define N_EDGES 3200000
#define F_IN 256
#define M_OUT 512            // 2*F_OUT concat
#define K_TOT 1024           // [x | Ax | A^2x | A^4x]
#define EPS_BN 1e-3f
#define NUM_CHUNKS 391       // ceil(100000/256)

typedef __attribute__((ext_vector_type(8))) short short8;
typedef __attribute__((ext_vector_type(4))) float floatx4;

__device__ __forceinline__ ushort f2b(float f) {
    union { float f; unsigned u; } c; c.f = f;
    unsigned u = c.u;
    unsigned r = (u + 0x7FFFu + ((u >> 16) & 1u)) >> 16;   // RNE
    return (ushort)r;
}
__device__ __forceinline__ float b2f(ushort b) {
    union { unsigned u; float f; } c; c.u = ((unsigned)b) << 16;
    return c.f;
}

// ---------------- small utility kernels ----------------

__global__ void zero_i32(int* __restrict__ p, int n) {
    int i = blockIdx.x * blockDim.x + threadIdx.x;
    if (i < n) p[i] = 0;
}

__global__ void hist_kernel(const int* __restrict__ row, int* __restrict__ counts, int n) {
    int i = blockIdx.x * blockDim.x + threadIdx.x;
    if (i < n) atomicAdd(&counts[row[i]], 1);
}

__global__ void scan_chunk_sums(const int* __restrict__ counts, int* __restrict__ chunkSums, int n) {
    __shared__ int sm[256];
    int c = blockIdx.x;
    int t = threadIdx.x;
    int i = c * 256 + t;
    sm[t] = (i < n) ? counts[i] : 0;
    __syncthreads();
    for (int s = 128; s > 0; s >>= 1) {
        if (t < s) sm[t] += sm[t + s];
        __syncthreads();
    }
    if (t == 0) chunkSums[c] = sm[0];
}

__global__ void scan_spine(int* __restrict__ chunkSums, int numChunks, int* __restrict__ row_off, int n) {
    __shared__ int sm[512];
    int t = threadIdx.x;
    int v = (t < numChunks) ? chunkSums[t] : 0;
    sm[t] = v;
    __syncthreads();
    for (int s = 1; s < 512; s <<= 1) {
        int add = (t >= s) ? sm[t - s] : 0;
        __syncthreads();
        sm[t] += add;
        __syncthreads();
    }
    if (t < numChunks) chunkSums[t] = sm[t] - v;   // exclusive
    if (t == 511) row_off[n] = sm[511];
}

__global__ void scan_final(const int* __restrict__ counts, const int* __restrict__ chunkSums,
                           int* __restrict__ row_off, int n) {
    __shared__ int sm[256];
    int c = blockIdx.x;
    int t = threadIdx.x;
    int i = c * 256 + t;
    int v = (i < n) ? counts[i] : 0;
    sm[t] = v;
    __syncthreads();
    for (int s = 1; s < 256; s <<= 1) {
        int add = (t >= s) ? sm[t - s] : 0;
        __syncthreads();
        sm[t] += add;
        __syncthreads();
    }
    if (i < n) row_off[i] = chunkSums[c] + sm[t] - v;
}

__global__ void scatter_kernel(const int* __restrict__ row, const int* __restrict__ col,
                               const float* __restrict__ val,
                               const int* __restrict__ row_off, int* __restrict__ cursor,
                               int* __restrict__ col_s, float* __restrict__ val_s, int n) {
    int i = blockIdx.x * blockDim.x + threadIdx.x;
    if (i < n) {
        int r = row[i];
        int pos = row_off[r] + atomicAdd(&cursor[r], 1);
        col_s[pos] = col[i];
        val_s[pos] = val[i];
    }
}

// ---------------- convert x -> bf16 segment of Ab ----------------

__global__ void convert_x(const float* __restrict__ x, ushort* __restrict__ Ab) {
    int gid = blockIdx.x * blockDim.x + threadIdx.x;       // one per 4 elems
    if (gid >= N_NODES * F_IN / 4) return;
    int li = gid * 4;
    int node = li >> 8;
    int c = li & 255;
    float4 v = *reinterpret_cast<const float4*>(&x[li]);
    ushort4 o;
    o.x = f2b(v.x); o.y = f2b(v.y); o.z = f2b(v.z); o.w = f2b(v.w);
    *reinterpret_cast<ushort4*>(&Ab[(size_t)node * K_TOT + c]) = o;
}

// ---------------- SpMM (bf16 in, bf16 out, fp32 accumulate) ----------------
// one wave per row; lane handles 4 consecutive features (ushort4 = 8 B)

__global__ void spmm_bf16(const int* __restrict__ row_off, const int* __restrict__ col_s,
                          const float* __restrict__ val_s,
                          const ushort* __restrict__ h, int hs,
                          ushort* __restrict__ y, int ys) {
    int wave = threadIdx.x >> 6;
    int lane = threadIdx.x & 63;
    int row = blockIdx.x * 4 + wave;
    if (row >= N_NODES) return;
    int s = row_off[row];
    int e = row_off[row + 1];
    float ax = 0.f, ay = 0.f, az = 0.f, aw = 0.f;
    for (int j = s; j < e; j++) {
        int c = col_s[j];
        float v = val_s[j];
        ushort4 hv = *reinterpret_cast<const ushort4*>(&h[(size_t)c * hs + lane * 4]);
        ax += v * b2f(hv.x);
        ay += v * b2f(hv.y);
        az += v * b2f(hv.z);
        aw += v * b2f(hv.w);
    }
    ushort4 o;
    o.x = f2b(ax); o.y = f2b(ay); o.z = f2b(az); o.w = f2b(aw);
    *reinterpret_cast<ushort4*>(&y[(size_t)row * ys + lane * 4]) = o;
}

// ---------------- weight / BN prep ----------------
// Wt: bf16, K-major: Wt[n][kg], n in 0..511, kg in 0..1023
// kg seg 0 = sum_j w{a,b}_x[j]; seg s=1..3 = w{a,b}_adj[s-1]

__global__ void build_weights_t(const float* __restrict__ wa_x, const float* __restrict__ wa_adj,
                                const float* __restrict__ wb_x, const float* __restrict__ wb_adj,
                                ushort* __restrict__ Wt) {
    int idx = blockIdx.x * blockDim.x + threadIdx.x;
    if (idx >= M_OUT * K_TOT) return;
    int n = idx >> 10;        // 0..511
    int kg = idx & 1023;      // 0..1023
    int seg = kg >> 8;
    int k = kg & 255;
    float w;
    if (seg == 0) {
        if (n < 256)
            w = wa_x[0 * 65536 + k * 256 + n] + wa_x[1 * 65536 + k * 256 + n] + wa_x[2 * 65536 + k * 256 + n];
        else {
            int nn = n - 256;
            w = wb_x[0 * 65536 + k * 256 + nn] + wb_x[1 * 65536 + k * 256 + nn] + wb_x[2 * 65536 + k * 256 + nn];
        }
    } else {
        int s = seg - 1;
        if (n < 256) w = wa_adj[s * 65536 + k * 256 + n];
        else         w = wb_adj[s * 65536 + k * 256 + (n - 256)];
    }
    Wt[idx] = f2b(w);
}

__global__ void build_bn(const float* __restrict__ ga, const float* __restrict__ ba,
                         const float* __restrict__ ma, const float* __restrict__ va,
                         const float* __restrict__ gb, const float* __restrict__ bb,
                         const float* __restrict__ mb, const float* __restrict__ vb,
                         float* __restrict__ scale, float* __restrict__ bias) {
    int c = blockIdx.x * blockDim.x + threadIdx.x;
    if (c >= 512) return;
    float g, b, m, v;
    if (c < 256) { g = ga[c]; b = ba[c]; m = ma[c]; v = va[c]; }
    else { int cc = c - 256; g = gb[cc]; b = bb[cc]; m = mb[cc]; v = vb[cc]; }
    float s = g / sqrtf(v + EPS_BN);
    scale[c] = s;
    bias[c] = b - m * s;
}

// ---------------- MFMA GEMM: C[N,512] = Ab[N,1024] @ Wt^T, fused relu+BN ----------------
// block = 256 threads = 4 waves (2x2), block tile 128x128, wave tile 64x64
// Ab row-major [m][k]; Wt K-major [n][k]  =>  both staged identically.
// LDS stride 40 elems (80 B): rows hit banks with period 8 -> 2-way (free).

#define LDS_STRIDE 40

__global__ void gemm_mfma(const ushort* __restrict__ Ab, const ushort* __restrict__ Wt,
                          float* __restrict__ C,
                          const float* __restrict__ scale, const float* __restrict__ bias) {
    __shared__ ushort As[128 * LDS_STRIDE];
    __shared__ ushort Bs[128 * LDS_STRIDE];
    const int tid = threadIdx.x;
    const int lane = tid & 63;
    const int wave = tid >> 6;
    const int wm = wave >> 1;       // wave row half (0/1)
    const int wn = wave & 1;        // wave col half (0/1)
    const int quad = lane >> 4;
    const int l16 = lane & 15;
    const int mBase = blockIdx.y * 128;
    const int nBase = blockIdx.x * 128;

    floatx4 acc[4][4];
#pragma unroll
    for (int i = 0; i < 4; i++)
#pragma unroll
        for (int j = 0; j < 4; j++) acc[i][j] = (floatx4){0.f, 0.f, 0.f, 0.f};

    for (int k0 = 0; k0 < K_TOT; k0 += 32) {
        // stage A and B tiles: 128 rows x 32 cols bf16 each
#pragma unroll
        for (int p = 0; p < 2; p++) {
            int li = tid + p * 256;
            int row = li >> 2;             // 0..127
            int c8 = (li & 3) * 8;         // 0,8,16,24
            int gm = mBase + row; if (gm > N_NODES - 1) gm = N_NODES - 1;
            uint4 va = *reinterpret_cast<const uint4*>(&Ab[(size_t)gm * K_TOT + k0 + c8]);
            uint4 vb = *reinterpret_cast<const uint4*>(&Wt[(size_t)(nBase + row) * K_TOT + k0 + c8]);
            *reinterpret_cast<uint4*>(&As[row * LDS_STRIDE + c8]) = va;
            *reinterpret_cast<uint4*>(&Bs[row * LDS_STRIDE + c8]) = vb;
        }
        __syncthreads();

        short8 a_frag[4], b_frag[4];
#pragma unroll
        for (int i = 0; i < 4; i++)
            a_frag[i] = *reinterpret_cast<const short8*>(&As[(wm * 64 + i * 16 + l16) * LDS_STRIDE + quad * 8]);
#pragma unroll
        for (int j = 0; j < 4; j++)
            b_frag[j] = *reinterpret_cast<const short8*>(&Bs[(wn * 64 + j * 16 + l16) * LDS_STRIDE + quad * 8]);
#pragma unroll
        for (int i = 0; i < 4; i++)
#pragma unroll
            for (int j = 0; j < 4; j++)
                acc[i][j] = __builtin_amdgcn_mfma_f32_16x16x32_bf16(a_frag[i], b_frag[j], acc[i][j], 0, 0, 0);
        __syncthreads();
    }

    // epilogue: relu on cols < 256, then BN affine; C row-major [m][512]
    float sc[4], bs[4];
    int gncol[4];
#pragma unroll
    for (int j = 0; j < 4; j++) {
        int gn = nBase + wn * 64 + j * 16 + l16;
        gncol[j] = gn;
        sc[j] = scale[gn];
        bs[j] = bias[gn];
    }
#pragma unroll
    for (int i = 0; i < 4; i++) {
#pragma unroll
        for (int r = 0; r < 4; r++) {
            int gm = mBase + wm * 64 + i * 16 + quad * 4 + r;
            if (gm >= N_NODES) continue;
#pragma unroll
            for (int j = 0; j < 4; j++) {
                float v = acc[i][j][r];
                if (gncol[j] < 256) v = fmaxf(v, 0.f);
                v = v * sc[j] + bs[j];
                C[(size_t)gm * M_OUT + gncol[j]] = v;
            }
        }
    }
}

// ---------------- launch ----------------

static inline size_t align_up(size_t x, size_t a) { return (x + a - 1) & ~(a - 1); }

extern "C" void kernel_launch(void* const* d_in, const int* in_sizes, int n_in,
                              void* d_out, int out_size, void* d_ws, size_t ws_size,
                              hipStream_t stream) {
    const float* x      = (const float*)d_in[0];
    const int*   erow   = (const int*)d_in[1];
    const int*   ecol   = (const int*)d_in[2];
    const float* eval   = (const float*)d_in[3];
    const float* wa_x   = (const float*)d_in[4];
    const float* wa_adj = (const float*)d_in[5];
    const float* wb_x   = (const float*)d_in[6];
    const float* wb_adj = (const float*)d_in[7];
    const float* ga = (const float*)d_in[8];
    const float* ba = (const float*)d_in[9];
    const float* ma = (const float*)d_in[10];
    const float* va = (const float*)d_in[11];
    const float* gb = (const float*)d_in[12];
    const float* bb = (const float*)d_in[13];
    const float* mb = (const float*)d_in[14];
    const float* vb = (const float*)d_in[15];
    float* out = (float*)d_out;

    char* ws = (char*)d_ws;
    size_t off = 0;
    int*    row_off   = (int*)(ws + off);    off = align_up(off + (size_t)(N_NODES + 1) * 4, 1024);
    int*    cursor    = (int*)(ws + off);    off = align_up(off + (size_t)N_NODES * 4, 1024);
    int*    chunkSums = (int*)(ws + off);    off = align_up(off + (size_t)NUM_CHUNKS * 4, 1024);
    int*    col_s     = (int*)(ws + off);    off = align_up(off + (size_t)N_EDGES * 4, 1024);
    float*  val_s     = (float*)(ws + off);  off = align_up(off + (size_t)N_EDGES * 4, 1024);
    ushort* Wt        = (ushort*)(ws + off); off = align_up(off + (size_t)M_OUT * K_TOT * 2, 1024);
    float*  scale     = (float*)(ws + off);  off = align_up(off + 512 * 4, 1024);
    float*  bias      = (float*)(ws + off);  off = align_up(off + 512 * 4, 1024);
    ushort* Ab        = (ushort*)(ws + off); off = align_up(off + (size_t)N_NODES * K_TOT * 2, 1024);
    ushort* tmp       = (ushort*)(ws + off); off = align_up(off + (size_t)N_NODES * F_IN * 2, 1024);
    (void)ws_size; (void)in_sizes; (void)n_in; (void)out_size;

    const int zeroBlocks = (N_NODES + 255) / 256;
    const int edgeBlocks = (N_EDGES + 255) / 256;

    // ---- CSR build ----
    zero_i32<<<zeroBlocks, 256, 0, stream>>>(cursor, N_NODES);
    hist_kernel<<<edgeBlocks, 256, 0, stream>>>(erow, cursor, N_EDGES);
    scan_chunk_sums<<<NUM_CHUNKS, 256, 0, stream>>>(cursor, chunkSums, N_NODES);
    scan_spine<<<1, 512, 0, stream>>>(chunkSums, NUM_CHUNKS, row_off, N_NODES);
    scan_final<<<NUM_CHUNKS, 256, 0, stream>>>(cursor, chunkSums, row_off, N_NODES);
    zero_i32<<<zeroBlocks, 256, 0, stream>>>(cursor, N_NODES);
    scatter_kernel<<<edgeBlocks, 256, 0, stream>>>(erow, ecol, eval, row_off, cursor,
                                                   col_s, val_s, N_EDGES);

    // ---- weight & BN prep ----
    build_weights_t<<<(M_OUT * K_TOT) / 256, 256, 0, stream>>>(wa_x, wa_adj, wb_x, wb_adj, Wt);
    build_bn<<<2, 256, 0, stream>>>(ga, ba, ma, va, gb, bb, mb, vb, scale, bias);

    // ---- x -> bf16 (segment 0 of Ab) ----
    convert_x<<<(N_NODES * F_IN / 4 + 255) / 256, 256, 0, stream>>>(x, Ab);

    // ---- hop chain (bf16 storage, fp32 accumulate) ----
    const int spmmBlocks = (N_NODES + 3) / 4;
    spmm_bf16<<<spmmBlocks, 256, 0, stream>>>(row_off, col_s, val_s,
                                              Ab + 0 * 256, K_TOT, Ab + 1 * 256, K_TOT);   // A x
    spmm_bf16<<<spmmBlocks, 256, 0, stream>>>(row_off, col_s, val_s,
                                              Ab + 1 * 256, K_TOT, Ab + 2 * 256, K_TOT);   // A^2 x
    spmm_bf16<<<spmmBlocks, 256, 0, stream>>>(row_off, col_s, val_s,
                                              Ab + 2 * 256, K_TOT, tmp, F_IN);             // A^3 x
    spmm_bf16<<<spmmBlocks, 256, 0, stream>>>(row_off, col_s, val_s,
                                              tmp, F_IN, Ab + 3 * 256, K_TOT);             // A^4 x

    // ---- fused GEMM + relu + BN ----
    dim3 gemmGrid(M_OUT / 128, (N_NODES + 127) / 128);
    gemm_mfma<<<gemmGrid, 256, 0, stream>>>(Ab, Wt, out, scale, bias);
}

// Round 3
// 1674.689 us; speedup vs baseline: 2.3838x; 1.2349x over previous
//
#include <hip/hip_runtime.h>
#include <math.h>

#define N_NODES 100000
#define N_EDGES 3200000
#define F_IN 256
#define M_OUT 512            // 2*F_OUT concat
#define K_TOT 1024           // [x | Ax | A^2x | A^4x]
#define EPS_BN 1e-3f
#define NUM_CHUNKS 391       // ceil(100000/256)

typedef __attribute__((ext_vector_type(8))) short short8;
typedef __attribute__((ext_vector_type(4))) float floatx4;

__device__ __forceinline__ ushort f2b(float f) {
    union { float f; unsigned u; } c; c.f = f;
    unsigned u = c.u;
    unsigned r = (u + 0x7FFFu + ((u >> 16) & 1u)) >> 16;   // RNE
    return (ushort)r;
}
__device__ __forceinline__ float b2f(ushort b) {
    union { unsigned u; float f; } c; c.u = ((unsigned)b) << 16;
    return c.f;
}

// ---------------- small utility kernels ----------------

__global__ void zero_i32(int* __restrict__ p, int n) {
    int i = blockIdx.x * blockDim.x + threadIdx.x;
    if (i < n) p[i] = 0;
}

__global__ void hist_kernel(const int* __restrict__ row, int* __restrict__ counts, int n) {
    int i = blockIdx.x * blockDim.x + threadIdx.x;
    if (i < n) atomicAdd(&counts[row[i]], 1);
}

__global__ void scan_chunk_sums(const int* __restrict__ counts, int* __restrict__ chunkSums, int n) {
    __shared__ int sm[256];
    int c = blockIdx.x;
    int t = threadIdx.x;
    int i = c * 256 + t;
    sm[t] = (i < n) ? counts[i] : 0;
    __syncthreads();
    for (int s = 128; s > 0; s >>= 1) {
        if (t < s) sm[t] += sm[t + s];
        __syncthreads();
    }
    if (t == 0) chunkSums[c] = sm[0];
}

__global__ void scan_spine(int* __restrict__ chunkSums, int numChunks, int* __restrict__ row_off, int n) {
    __shared__ int sm[512];
    int t = threadIdx.x;
    int v = (t < numChunks) ? chunkSums[t] : 0;
    sm[t] = v;
    __syncthreads();
    for (int s = 1; s < 512; s <<= 1) {
        int add = (t >= s) ? sm[t - s] : 0;
        __syncthreads();
        sm[t] += add;
        __syncthreads();
    }
    if (t < numChunks) chunkSums[t] = sm[t] - v;   // exclusive
    if (t == 511) row_off[n] = sm[511];
}

__global__ void scan_final(const int* __restrict__ counts, const int* __restrict__ chunkSums,
                           int* __restrict__ row_off, int n) {
    __shared__ int sm[256];
    int c = blockIdx.x;
    int t = threadIdx.x;
    int i = c * 256 + t;
    int v = (i < n) ? counts[i] : 0;
    sm[t] = v;
    __syncthreads();
    for (int s = 1; s < 256; s <<= 1) {
        int add = (t >= s) ? sm[t - s] : 0;
        __syncthreads();
        sm[t] += add;
        __syncthreads();
    }
    if (i < n) row_off[i] = chunkSums[c] + sm[t] - v;
}

__global__ void scatter_kernel(const int* __restrict__ row, const int* __restrict__ col,
                               const float* __restrict__ val,
                               const int* __restrict__ row_off, int* __restrict__ cursor,
                               int* __restrict__ col_s, float* __restrict__ val_s, int n) {
    int i = blockIdx.x * blockDim.x + threadIdx.x;
    if (i < n) {
        int r = row[i];
        int pos = row_off[r] + atomicAdd(&cursor[r], 1);
        col_s[pos] = col[i];
        val_s[pos] = val[i];
    }
}

// ---------------- convert x -> bf16 segment of Ab ----------------

__global__ void convert_x(const float* __restrict__ x, ushort* __restrict__ Ab) {
    int gid = blockIdx.x * blockDim.x + threadIdx.x;       // one per 4 elems
    if (gid >= N_NODES * F_IN / 4) return;
    int li = gid * 4;
    int node = li >> 8;
    int c = li & 255;
    float4 v = *reinterpret_cast<const float4*>(&x[li]);
    ushort4 o;
    o.x = f2b(v.x); o.y = f2b(v.y); o.z = f2b(v.z); o.w = f2b(v.w);
    *reinterpret_cast<ushort4*>(&Ab[(size_t)node * K_TOT + c]) = o;
}

// ---------------- SpMM (bf16 in, bf16 out, fp32 accumulate) ----------------
// one wave per row; lane handles 4 consecutive features (ushort4 = 8 B).
// R3: manual unroll-by-8 software pipeline — 8 independent gathers in flight,
// dual FMA accumulator chains. (R2 version compiled to VGPR=12, 1 gather in
// flight -> latency-bound at 22% VALUBusy / 32% HBM.)

__global__ void spmm_bf16(const int* __restrict__ row_off, const int* __restrict__ col_s,
                          const float* __restrict__ val_s,
                          const ushort* __restrict__ h, int hs,
                          ushort* __restrict__ y, int ys) {
    int wave = threadIdx.x >> 6;
    int lane = threadIdx.x & 63;
    int row = blockIdx.x * 4 + wave;
    if (row >= N_NODES) return;
    int s = row_off[row];
    int e = row_off[row + 1];
    const size_t loff = (size_t)lane * 4;

    float ax0 = 0.f, ay0 = 0.f, az0 = 0.f, aw0 = 0.f;
    float ax1 = 0.f, ay1 = 0.f, az1 = 0.f, aw1 = 0.f;

    int j = s;
    for (; j + 8 <= e; j += 8) {
        int   c[8];
        float v[8];
#pragma unroll
        for (int u = 0; u < 8; u++) { c[u] = col_s[j + u]; v[u] = val_s[j + u]; }
        ushort4 g[8];
#pragma unroll
        for (int u = 0; u < 8; u++)
            g[u] = *reinterpret_cast<const ushort4*>(&h[(size_t)c[u] * hs + loff]);
#pragma unroll
        for (int u = 0; u < 8; u += 2) {
            ax0 += v[u] * b2f(g[u].x);
            ay0 += v[u] * b2f(g[u].y);
            az0 += v[u] * b2f(g[u].z);
            aw0 += v[u] * b2f(g[u].w);
            ax1 += v[u + 1] * b2f(g[u + 1].x);
            ay1 += v[u + 1] * b2f(g[u + 1].y);
            az1 += v[u + 1] * b2f(g[u + 1].z);
            aw1 += v[u + 1] * b2f(g[u + 1].w);
        }
    }
    for (; j < e; j++) {
        int c = col_s[j];
        float v = val_s[j];
        ushort4 hv = *reinterpret_cast<const ushort4*>(&h[(size_t)c * hs + loff]);
        ax0 += v * b2f(hv.x);
        ay0 += v * b2f(hv.y);
        az0 += v * b2f(hv.z);
        aw0 += v * b2f(hv.w);
    }
    ushort4 o;
    o.x = f2b(ax0 + ax1);
    o.y = f2b(ay0 + ay1);
    o.z = f2b(az0 + az1);
    o.w = f2b(aw0 + aw1);
    *reinterpret_cast<ushort4*>(&y[(size_t)row * ys + lane * 4]) = o;
}

// ---------------- weight / BN prep ----------------
// Wt: bf16, K-major: Wt[n][kg], n in 0..511, kg in 0..1023
// kg seg 0 = sum_j w{a,b}_x[j]; seg s=1..3 = w{a,b}_adj[s-1]

__global__ void build_weights_t(const float* __restrict__ wa_x, const float* __restrict__ wa_adj,
                                const float* __restrict__ wb_x, const float* __restrict__ wb_adj,
                                ushort* __restrict__ Wt) {
    int idx = blockIdx.x * blockDim.x + threadIdx.x;
    if (idx >= M_OUT * K_TOT) return;
    int n = idx >> 10;        // 0..511
    int kg = idx & 1023;      // 0..1023
    int seg = kg >> 8;
    int k = kg & 255;
    float w;
    if (seg == 0) {
        if (n < 256)
            w = wa_x[0 * 65536 + k * 256 + n] + wa_x[1 * 65536 + k * 256 + n] + wa_x[2 * 65536 + k * 256 + n];
        else {
            int nn = n - 256;
            w = wb_x[0 * 65536 + k * 256 + nn] + wb_x[1 * 65536 + k * 256 + nn] + wb_x[2 * 65536 + k * 256 + nn];
        }
    } else {
        int s = seg - 1;
        if (n < 256) w = wa_adj[s * 65536 + k * 256 + n];
        else         w = wb_adj[s * 65536 + k * 256 + (n - 256)];
    }
    Wt[idx] = f2b(w);
}

__global__ void build_bn(const float* __restrict__ ga, const float* __restrict__ ba,
                         const float* __restrict__ ma, const float* __restrict__ va,
                         const float* __restrict__ gb, const float* __restrict__ bb,
                         const float* __restrict__ mb, const float* __restrict__ vb,
                         float* __restrict__ scale, float* __restrict__ bias) {
    int c = blockIdx.x * blockDim.x + threadIdx.x;
    if (c >= 512) return;
    float g, b, m, v;
    if (c < 256) { g = ga[c]; b = ba[c]; m = ma[c]; v = va[c]; }
    else { int cc = c - 256; g = gb[cc]; b = bb[cc]; m = mb[cc]; v = vb[cc]; }
    float s = g / sqrtf(v + EPS_BN);
    scale[c] = s;
    bias[c] = b - m * s;
}

// ---------------- MFMA GEMM: C[N,512] = Ab[N,1024] @ Wt^T, fused relu+BN ----------------
// block = 256 threads = 4 waves (2x2), block tile 128x128, wave tile 64x64
// Ab row-major [m][k]; Wt K-major [n][k]  =>  both staged identically.
// LDS stride 40 elems (80 B): rows hit banks with period 8 -> 2-way (free).

#define LDS_STRIDE 40

__global__ void gemm_mfma(const ushort* __restrict__ Ab, const ushort* __restrict__ Wt,
                          float* __restrict__ C,
                          const float* __restrict__ scale, const float* __restrict__ bias) {
    __shared__ ushort As[128 * LDS_STRIDE];
    __shared__ ushort Bs[128 * LDS_STRIDE];
    const int tid = threadIdx.x;
    const int lane = tid & 63;
    const int wave = tid >> 6;
    const int wm = wave >> 1;       // wave row half (0/1)
    const int wn = wave & 1;        // wave col half (0/1)
    const int quad = lane >> 4;
    const int l16 = lane & 15;
    const int mBase = blockIdx.y * 128;
    const int nBase = blockIdx.x * 128;

    floatx4 acc[4][4];
#pragma unroll
    for (int i = 0; i < 4; i++)
#pragma unroll
        for (int j = 0; j < 4; j++) acc[i][j] = (floatx4){0.f, 0.f, 0.f, 0.f};

    for (int k0 = 0; k0 < K_TOT; k0 += 32) {
        // stage A and B tiles: 128 rows x 32 cols bf16 each
#pragma unroll
        for (int p = 0; p < 2; p++) {
            int li = tid + p * 256;
            int row = li >> 2;             // 0..127
            int c8 = (li & 3) * 8;         // 0,8,16,24
            int gm = mBase + row; if (gm > N_NODES - 1) gm = N_NODES - 1;
            uint4 va = *reinterpret_cast<const uint4*>(&Ab[(size_t)gm * K_TOT + k0 + c8]);
            uint4 vb = *reinterpret_cast<const uint4*>(&Wt[(size_t)(nBase + row) * K_TOT + k0 + c8]);
            *reinterpret_cast<uint4*>(&As[row * LDS_STRIDE + c8]) = va;
            *reinterpret_cast<uint4*>(&Bs[row * LDS_STRIDE + c8]) = vb;
        }
        __syncthreads();

        short8 a_frag[4], b_frag[4];
#pragma unroll
        for (int i = 0; i < 4; i++)
            a_frag[i] = *reinterpret_cast<const short8*>(&As[(wm * 64 + i * 16 + l16) * LDS_STRIDE + quad * 8]);
#pragma unroll
        for (int j = 0; j < 4; j++)
            b_frag[j] = *reinterpret_cast<const short8*>(&Bs[(wn * 64 + j * 16 + l16) * LDS_STRIDE + quad * 8]);
#pragma unroll
        for (int i = 0; i < 4; i++)
#pragma unroll
            for (int j = 0; j < 4; j++)
                acc[i][j] = __builtin_amdgcn_mfma_f32_16x16x32_bf16(a_frag[i], b_frag[j], acc[i][j], 0, 0, 0);
        __syncthreads();
    }

    // epilogue: relu on cols < 256, then BN affine; C row-major [m][512]
    float sc[4], bs[4];
    int gncol[4];
#pragma unroll
    for (int j = 0; j < 4; j++) {
        int gn = nBase + wn * 64 + j * 16 + l16;
        gncol[j] = gn;
        sc[j] = scale[gn];
        bs[j] = bias[gn];
    }
#pragma unroll
    for (int i = 0; i < 4; i++) {
#pragma unroll
        for (int r = 0; r < 4; r++) {
            int gm = mBase + wm * 64 + i * 16 + quad * 4 + r;
            if (gm >= N_NODES) continue;
#pragma unroll
            for (int j = 0; j < 4; j++) {
                float v = acc[i][j][r];
                if (gncol[j] < 256) v = fmaxf(v, 0.f);
                v = v * sc[j] + bs[j];
                C[(size_t)gm * M_OUT + gncol[j]] = v;
            }
        }
    }
}

// ---------------- launch ----------------

static inline size_t align_up(size_t x, size_t a) { return (x + a - 1) & ~(a - 1); }

extern "C" void kernel_launch(void* const* d_in, const int* in_sizes, int n_in,
                              void* d_out, int out_size, void* d_ws, size_t ws_size,
                              hipStream_t stream) {
    const float* x      = (const float*)d_in[0];
    const int*   erow   = (const int*)d_in[1];
    const int*   ecol   = (const int*)d_in[2];
    const float* eval   = (const float*)d_in[3];
    const float* wa_x   = (const float*)d_in[4];
    const float* wa_adj = (const float*)d_in[5];
    const float* wb_x   = (const float*)d_in[6];
    const float* wb_adj = (const float*)d_in[7];
    const float* ga = (const float*)d_in[8];
    const float* ba = (const float*)d_in[9];
    const float* ma = (const float*)d_in[10];
    const float* va = (const float*)d_in[11];
    const float* gb = (const float*)d_in[12];
    const float* bb = (const float*)d_in[13];
    const float* mb = (const float*)d_in[14];
    const float* vb = (const float*)d_in[15];
    float* out = (float*)d_out;

    char* ws = (char*)d_ws;
    size_t off = 0;
    int*    row_off   = (int*)(ws + off);    off = align_up(off + (size_t)(N_NODES + 1) * 4, 1024);
    int*    cursor    = (int*)(ws + off);    off = align_up(off + (size_t)N_NODES * 4, 1024);
    int*    chunkSums = (int*)(ws + off);    off = align_up(off + (size_t)NUM_CHUNKS * 4, 1024);
    int*    col_s     = (int*)(ws + off);    off = align_up(off + (size_t)N_EDGES * 4, 1024);
    float*  val_s     = (float*)(ws + off);  off = align_up(off + (size_t)N_EDGES * 4, 1024);
    ushort* Wt        = (ushort*)(ws + off); off = align_up(off + (size_t)M_OUT * K_TOT * 2, 1024);
    float*  scale     = (float*)(ws + off);  off = align_up(off + 512 * 4, 1024);
    float*  bias      = (float*)(ws + off);  off = align_up(off + 512 * 4, 1024);
    ushort* Ab        = (ushort*)(ws + off); off = align_up(off + (size_t)N_NODES * K_TOT * 2, 1024);
    ushort* tmp       = (ushort*)(ws + off); off = align_up(off + (size_t)N_NODES * F_IN * 2, 1024);
    (void)ws_size; (void)in_sizes; (void)n_in; (void)out_size;

    const int zeroBlocks = (N_NODES + 255) / 256;
    const int edgeBlocks = (N_EDGES + 255) / 256;

    // ---- CSR build ----
    zero_i32<<<zeroBlocks, 256, 0, stream>>>(cursor, N_NODES);
    hist_kernel<<<edgeBlocks, 256, 0, stream>>>(erow, cursor, N_EDGES);
    scan_chunk_sums<<<NUM_CHUNKS, 256, 0, stream>>>(cursor, chunkSums, N_NODES);
    scan_spine<<<1, 512, 0, stream>>>(chunkSums, NUM_CHUNKS, row_off, N_NODES);
    scan_final<<<NUM_CHUNKS, 256, 0, stream>>>(cursor, chunkSums, row_off, N_NODES);
    zero_i32<<<zeroBlocks, 256, 0, stream>>>(cursor, N_NODES);
    scatter_kernel<<<edgeBlocks, 256, 0, stream>>>(erow, ecol, eval, row_off, cursor,
                                                   col_s, val_s, N_EDGES);

    // ---- weight & BN prep ----
    build_weights_t<<<(M_OUT * K_TOT) / 256, 256, 0, stream>>>(wa_x, wa_adj, wb_x, wb_adj, Wt);
    build_bn<<<2, 256, 0, stream>>>(ga, ba, ma, va, gb, bb, mb, vb, scale, bias);

    // ---- x -> bf16 (segment 0 of Ab) ----
    convert_x<<<(N_NODES * F_IN / 4 + 255) / 256, 256, 0, stream>>>(x, Ab);

    // ---- hop chain (bf16 storage, fp32 accumulate) ----
    const int spmmBlocks = (N_NODES + 3) / 4;
    spmm_bf16<<<spmmBlocks, 256, 0, stream>>>(row_off, col_s, val_s,
                                              Ab + 0 * 256, K_TOT, Ab + 1 * 256, K_TOT);   // A x
    spmm_bf16<<<spmmBlocks, 256, 0, stream>>>(row_off, col_s, val_s,
                                              Ab + 1 * 256, K_TOT, Ab + 2 * 256, K_TOT);   // A^2 x
    spmm_bf16<<<spmmBlocks, 256, 0, stream>>>(row_off, col_s, val_s,
                                              Ab + 2 * 256, K_TOT, tmp, F_IN);             // A^3 x
    spmm_bf16<<<spmmBlocks, 256, 0, stream>>>(row_off, col_s, val_s,
                                              tmp, F_IN, Ab + 3 * 256, K_TOT);             // A^4 x

    // ---- fused GEMM + relu + BN ----
    dim3 gemmGrid(M_OUT / 128, (N_NODES + 127) / 128);
    gemm_mfma<<<gemmGrid, 256, 0, stream>>>(Ab, Wt, out, scale, bias);
}